// Round 7
// baseline (99.562 us; speedup 1.0000x reference)
//
#include <hip/hip_runtime.h>

#define SEQL 512
#define PREDL 96
#define NB 9          // 1 + 2*4 basis functions (DC, cos/sin k=1..4)
#define WBPAD 12      // padded stride for WB rows
#define RU1 8         // rows per wave-iter, coef kernel
#define RU2 4         // rows per wave-iter, apply kernel
#define RUF 4         // rows per wave-iter, fused fallback

typedef float fvec4 __attribute__((ext_vector_type(4)));

// Full-wave sum via DPP (VALU pipe only), broadcast through SGPR readlane(63).
__device__ __forceinline__ float wave_sum_bcast(float v) {
    int t;
    t = __builtin_amdgcn_update_dpp(0, __float_as_int(v), 0x111, 0xf, 0xf, true); v += __int_as_float(t); // shr 1
    t = __builtin_amdgcn_update_dpp(0, __float_as_int(v), 0x112, 0xf, 0xf, true); v += __int_as_float(t); // shr 2
    t = __builtin_amdgcn_update_dpp(0, __float_as_int(v), 0x114, 0xf, 0xf, true); v += __int_as_float(t); // shr 4
    t = __builtin_amdgcn_update_dpp(0, __float_as_int(v), 0x118, 0xf, 0xf, true); v += __int_as_float(t); // shr 8
    t = __builtin_amdgcn_update_dpp(0, __float_as_int(v), 0x142, 0xf, 0xf, true); v += __int_as_float(t); // bcast15
    t = __builtin_amdgcn_update_dpp(0, __float_as_int(v), 0x143, 0xf, 0xf, true); v += __int_as_float(t); // bcast31
    return __int_as_float(__builtin_amdgcn_readlane(__float_as_int(v), 63));
}

// ---------------- setup kernel 1: basis table (j-major) --------------------------
__global__ void basis_kernel(float* __restrict__ tbl) {
    int s = threadIdx.x;
    if (s >= SEQL) return;
    tbl[0 * SEQL + s] = 1.0f;
    #pragma unroll
    for (int k = 1; k <= 4; ++k) {
        int m = (k * s) & (SEQL - 1);              // exact periodic reduction
        float ang = (float)m * (6.283185307179586f / SEQL);
        float sn, cs;
        __sincosf(ang, &sn, &cs);
        tbl[(2 * k - 1) * SEQL + s] = cs;
        tbl[(2 * k    ) * SEQL + s] = sn;
    }
}

// ---------------- setup kernel 2: WB[p][j] = basis_j . W[p] ----------------------
__global__ __launch_bounds__(64)
void wb_kernel(const float* __restrict__ W, const float* __restrict__ tbl,
               float* __restrict__ wb) {
    int p = blockIdx.x;          // 0..95
    int lane = threadIdx.x;      // 0..63
    const float* wr = W + (size_t)p * SEQL + lane * 8;
    float4 wa = *(const float4*)(wr);
    float4 wz = *(const float4*)(wr + 4);
    float wv[8] = {wa.x, wa.y, wa.z, wa.w, wz.x, wz.y, wz.z, wz.w};
    #pragma unroll
    for (int j = 0; j < NB; ++j) {
        const float* bj = tbl + j * SEQL + lane * 8;
        float4 b0 = *(const float4*)bj;
        float4 b1 = *(const float4*)(bj + 4);
        float bb[8] = {b0.x, b0.y, b0.z, b0.w, b1.x, b1.y, b1.z, b1.w};
        float acc = 0.f;
        #pragma unroll
        for (int e = 0; e < 8; ++e) acc += wv[e] * bb[e];
        float s = wave_sum_bcast(acc);
        if (lane == 0) wb[p * WBPAD + j] = s;
    }
}

// ---------------- K1: coefficients only (read x, write 2.4 MB) -------------------
__global__ __launch_bounds__(256)
void coef_kernel(const float* __restrict__ x, const float* __restrict__ tbl,
                 float* __restrict__ cbuf, int nrows) {
    const int lane = threadIdx.x & 63;
    const int wid  = threadIdx.x >> 6;
    const int gw   = blockIdx.x * (blockDim.x >> 6) + wid;
    const int nw   = gridDim.x * (blockDim.x >> 6);

    float bas[NB][8];
    #pragma unroll
    for (int j = 0; j < NB; ++j) {
        const float* bj = tbl + j * SEQL + lane * 8;
        float4 b0 = *(const float4*)bj;
        float4 b1 = *(const float4*)(bj + 4);
        bas[j][0] = b0.x; bas[j][1] = b0.y; bas[j][2] = b0.z; bas[j][3] = b0.w;
        bas[j][4] = b1.x; bas[j][5] = b1.y; bas[j][6] = b1.z; bas[j][7] = b1.w;
    }

    for (int r0 = gw * RU1; r0 < nrows; r0 += nw * RU1) {
        float4 xl[RU1][2];
        #pragma unroll
        for (int u = 0; u < RU1; ++u) {
            const float* xr = x + (size_t)(r0 + u) * SEQL + lane * 8;
            xl[u][0] = *(const float4*)xr;
            xl[u][1] = *(const float4*)(xr + 4);
        }
        #pragma unroll
        for (int u = 0; u < RU1; ++u) {
            float xv[8] = {xl[u][0].x, xl[u][0].y, xl[u][0].z, xl[u][0].w,
                           xl[u][1].x, xl[u][1].y, xl[u][1].z, xl[u][1].w};
            float acc[NB];
            #pragma unroll
            for (int j = 0; j < NB; ++j) acc[j] = 0.f;
            #pragma unroll
            for (int e = 0; e < 8; ++e)
                #pragma unroll
                for (int j = 0; j < NB; ++j) acc[j] += xv[e] * bas[j][e];
            acc[0] *= (1.0f / SEQL);
            #pragma unroll
            for (int j = 1; j < NB; ++j) acc[j] *= (2.0f / SEQL);
            float c[NB];
            #pragma unroll
            for (int j = 0; j < NB; ++j) c[j] = wave_sum_bcast(acc[j]);
            // lane j < 9 stores c[j]: select via cndmask chain (static indexing)
            float v = c[0];
            #pragma unroll
            for (int j = 1; j < NB; ++j) v = (lane == j) ? c[j] : v;
            if (lane < NB) cbuf[(size_t)(r0 + u) * NB + lane] = v;
        }
    }
}

// ---------------- K2: apply (re-read x from L3, write resid + fc) ----------------
__global__ __launch_bounds__(256)
void apply_kernel(const float* __restrict__ x, const float* __restrict__ bias,
                  const float* __restrict__ tbl, const float* __restrict__ wb,
                  const float* __restrict__ cbuf,
                  float* __restrict__ fc, float* __restrict__ resid, int nrows) {
    const int lane = threadIdx.x & 63;
    const int wid  = threadIdx.x >> 6;
    const int gw   = blockIdx.x * (blockDim.x >> 6) + wid;
    const int nw   = gridDim.x * (blockDim.x >> 6);

    float bas[NB][8];
    #pragma unroll
    for (int j = 0; j < NB; ++j) {
        const float* bj = tbl + j * SEQL + lane * 8;
        float4 b0 = *(const float4*)bj;
        float4 b1 = *(const float4*)(bj + 4);
        bas[j][0] = b0.x; bas[j][1] = b0.y; bas[j][2] = b0.z; bas[j][3] = b0.w;
        bas[j][4] = b1.x; bas[j][5] = b1.y; bas[j][6] = b1.z; bas[j][7] = b1.w;
    }
    const int p0 = lane;
    const int p1 = 64 + lane;
    float wb0[NB], wb1[NB], bv0, bv1 = 0.f;
    #pragma unroll
    for (int j = 0; j < NB; ++j) wb0[j] = wb[p0 * WBPAD + j];
    bv0 = bias[p0];
    if (lane < 32) {
        #pragma unroll
        for (int j = 0; j < NB; ++j) wb1[j] = wb[p1 * WBPAD + j];
        bv1 = bias[p1];
    }

    for (int r0 = gw * RU2; r0 < nrows; r0 += nw * RU2) {
        float4 xl[RU2][2];
        #pragma unroll
        for (int u = 0; u < RU2; ++u) {
            const float* xr = x + (size_t)(r0 + u) * SEQL + lane * 8;
            xl[u][0] = *(const float4*)xr;
            xl[u][1] = *(const float4*)(xr + 4);
        }
        // one coalesced load covers all RU2*NB=36 coefficients; broadcast by shfl
        float cmy = (lane < RU2 * NB) ? cbuf[(size_t)r0 * NB + lane] : 0.f;

        #pragma unroll
        for (int u = 0; u < RU2; ++u) {
            float c[NB];
            #pragma unroll
            for (int j = 0; j < NB; ++j) c[j] = __shfl(cmy, u * NB + j, 64);

            float xv[8] = {xl[u][0].x, xl[u][0].y, xl[u][0].z, xl[u][0].w,
                           xl[u][1].x, xl[u][1].y, xl[u][1].z, xl[u][1].w};
            float rv[8];
            #pragma unroll
            for (int e = 0; e < 8; ++e) {
                float t = 0.f;
                #pragma unroll
                for (int j = 0; j < NB; ++j) t += c[j] * bas[j][e];
                rv[e] = xv[e] - t;
            }
            float* rr = resid + (size_t)(r0 + u) * SEQL + lane * 8;
            fvec4 v0 = {rv[0], rv[1], rv[2], rv[3]};
            fvec4 v1 = {rv[4], rv[5], rv[6], rv[7]};
            __builtin_nontemporal_store(v0, (fvec4*)rr);
            __builtin_nontemporal_store(v1, (fvec4*)(rr + 4));

            float* fr = fc + (size_t)(r0 + u) * PREDL;
            float f0 = bv0;
            #pragma unroll
            for (int j = 0; j < NB; ++j) f0 += c[j] * wb0[j];
            __builtin_nontemporal_store(f0, fr + p0);
            if (lane < 32) {
                float f1 = bv1;
                #pragma unroll
                for (int j = 0; j < NB; ++j) f1 += c[j] * wb1[j];
                __builtin_nontemporal_store(f1, fr + p1);
            }
        }
    }
}

// ---------------- fused fallback (round-3 structure) if ws too small -------------
__global__ __launch_bounds__(256)
void detrend_kernel(const float* __restrict__ x, const float* __restrict__ bias,
                    const float* __restrict__ tbl, const float* __restrict__ wb,
                    float* __restrict__ fc, float* __restrict__ resid, int nrows) {
    const int lane = threadIdx.x & 63;
    const int wid  = threadIdx.x >> 6;
    const int gw   = blockIdx.x * (blockDim.x >> 6) + wid;
    const int nw   = gridDim.x * (blockDim.x >> 6);

    float bas[NB][8];
    #pragma unroll
    for (int j = 0; j < NB; ++j) {
        const float* bj = tbl + j * SEQL + lane * 8;
        float4 b0 = *(const float4*)bj;
        float4 b1 = *(const float4*)(bj + 4);
        bas[j][0] = b0.x; bas[j][1] = b0.y; bas[j][2] = b0.z; bas[j][3] = b0.w;
        bas[j][4] = b1.x; bas[j][5] = b1.y; bas[j][6] = b1.z; bas[j][7] = b1.w;
    }
    const int p0 = lane;
    const int p1 = 64 + lane;
    float wb0[NB], wb1[NB], bv0, bv1 = 0.f;
    #pragma unroll
    for (int j = 0; j < NB; ++j) wb0[j] = wb[p0 * WBPAD + j];
    bv0 = bias[p0];
    if (lane < 32) {
        #pragma unroll
        for (int j = 0; j < NB; ++j) wb1[j] = wb[p1 * WBPAD + j];
        bv1 = bias[p1];
    }

    for (int r0 = gw * RUF; r0 < nrows; r0 += nw * RUF) {
        float4 xl[RUF][2];
        #pragma unroll
        for (int u = 0; u < RUF; ++u) {
            const float* xr = x + (size_t)(r0 + u) * SEQL + lane * 8;
            xl[u][0] = *(const float4*)xr;
            xl[u][1] = *(const float4*)(xr + 4);
        }
        #pragma unroll
        for (int u = 0; u < RUF; ++u) {
            float xv[8] = {xl[u][0].x, xl[u][0].y, xl[u][0].z, xl[u][0].w,
                           xl[u][1].x, xl[u][1].y, xl[u][1].z, xl[u][1].w};
            float acc[NB];
            #pragma unroll
            for (int j = 0; j < NB; ++j) acc[j] = 0.f;
            #pragma unroll
            for (int e = 0; e < 8; ++e)
                #pragma unroll
                for (int j = 0; j < NB; ++j) acc[j] += xv[e] * bas[j][e];
            acc[0] *= (1.0f / SEQL);
            #pragma unroll
            for (int j = 1; j < NB; ++j) acc[j] *= (2.0f / SEQL);
            float c[NB];
            #pragma unroll
            for (int j = 0; j < NB; ++j) c[j] = wave_sum_bcast(acc[j]);

            float rv[8];
            #pragma unroll
            for (int e = 0; e < 8; ++e) {
                float t = 0.f;
                #pragma unroll
                for (int j = 0; j < NB; ++j) t += c[j] * bas[j][e];
                rv[e] = xv[e] - t;
            }
            float* rr = resid + (size_t)(r0 + u) * SEQL + lane * 8;
            fvec4 v0 = {rv[0], rv[1], rv[2], rv[3]};
            fvec4 v1 = {rv[4], rv[5], rv[6], rv[7]};
            __builtin_nontemporal_store(v0, (fvec4*)rr);
            __builtin_nontemporal_store(v1, (fvec4*)(rr + 4));

            float* fr = fc + (size_t)(r0 + u) * PREDL;
            float f0 = bv0;
            #pragma unroll
            for (int j = 0; j < NB; ++j) f0 += c[j] * wb0[j];
            __builtin_nontemporal_store(f0, fr + p0);
            if (lane < 32) {
                float f1 = bv1;
                #pragma unroll
                for (int j = 0; j < NB; ++j) f1 += c[j] * wb1[j];
                __builtin_nontemporal_store(f1, fr + p1);
            }
        }
    }
}

extern "C" void kernel_launch(void* const* d_in, const int* in_sizes, int n_in,
                              void* d_out, int out_size, void* d_ws, size_t ws_size,
                              hipStream_t stream) {
    const float* x = (const float*)d_in[0];
    const float* W = (const float*)d_in[1];
    const float* b = (const float*)d_in[2];
    float* fc = (float*)d_out;
    const int nrows = in_sizes[0] / SEQL;            // 65536
    float* resid = fc + (size_t)nrows * PREDL;
    float* tbl = (float*)d_ws;                       // 9*512 floats
    float* wb  = tbl + NB * SEQL;                    // 96*12 floats
    float* cbuf = wb + PREDL * WBPAD;                // nrows*9 floats (2.36 MB)
    const size_t ws_need = ((size_t)NB * SEQL + PREDL * WBPAD + (size_t)nrows * NB) * 4;

    hipLaunchKernelGGL(basis_kernel, dim3(1), dim3(SEQL), 0, stream, tbl);
    hipLaunchKernelGGL(wb_kernel, dim3(PREDL), dim3(64), 0, stream, W, tbl, wb);

    if (ws_size >= ws_need) {
        // K1: 1024 blocks x 4 waves x 8 rows = 32768 rows/round -> 2 iterations
        hipLaunchKernelGGL(coef_kernel, dim3(1024), dim3(256), 0, stream,
                           x, tbl, cbuf, nrows);
        // K2: 1024 blocks x 4 waves x 4 rows = 16384 rows/round -> 4 iterations
        hipLaunchKernelGGL(apply_kernel, dim3(1024), dim3(256), 0, stream,
                           x, b, tbl, wb, cbuf, fc, resid, nrows);
    } else {
        hipLaunchKernelGGL(detrend_kernel, dim3(2048), dim3(256), 0, stream,
                           x, b, tbl, wb, fc, resid, nrows);
    }
}

// Round 8
// 60.469 us; speedup vs baseline: 1.6465x; 1.6465x over previous
//
#include <hip/hip_runtime.h>

#define SEQL 512
#define PREDL 96
#define NB 9          // 1 + 2*4 basis functions (DC, cos/sin k=1..4)
#define WBPAD 12      // padded stride for WB rows
#define RU 4          // rows per wave per iteration

typedef float fvec4 __attribute__((ext_vector_type(4)));

// Full-wave sum via DPP (VALU pipe only), broadcast through SGPR readlane(63).
__device__ __forceinline__ float wave_sum_bcast(float v) {
    int t;
    t = __builtin_amdgcn_update_dpp(0, __float_as_int(v), 0x111, 0xf, 0xf, true); v += __int_as_float(t); // shr 1
    t = __builtin_amdgcn_update_dpp(0, __float_as_int(v), 0x112, 0xf, 0xf, true); v += __int_as_float(t); // shr 2
    t = __builtin_amdgcn_update_dpp(0, __float_as_int(v), 0x114, 0xf, 0xf, true); v += __int_as_float(t); // shr 4
    t = __builtin_amdgcn_update_dpp(0, __float_as_int(v), 0x118, 0xf, 0xf, true); v += __int_as_float(t); // shr 8
    t = __builtin_amdgcn_update_dpp(0, __float_as_int(v), 0x142, 0xf, 0xf, true); v += __int_as_float(t); // bcast15
    t = __builtin_amdgcn_update_dpp(0, __float_as_int(v), 0x143, 0xf, 0xf, true); v += __int_as_float(t); // bcast31
    return __int_as_float(__builtin_amdgcn_readlane(__float_as_int(v), 63));
}

// ---------------- setup kernel 1: basis table (j-major) --------------------------
__global__ void basis_kernel(float* __restrict__ tbl) {
    int s = threadIdx.x;
    if (s >= SEQL) return;
    tbl[0 * SEQL + s] = 1.0f;
    #pragma unroll
    for (int k = 1; k <= 4; ++k) {
        int m = (k * s) & (SEQL - 1);              // exact periodic reduction
        float ang = (float)m * (6.283185307179586f / SEQL);
        float sn, cs;
        __sincosf(ang, &sn, &cs);
        tbl[(2 * k - 1) * SEQL + s] = cs;
        tbl[(2 * k    ) * SEQL + s] = sn;
    }
}

// ---------------- setup kernel 2: WB[p][j] = basis_j . W[p] ----------------------
__global__ __launch_bounds__(64)
void wb_kernel(const float* __restrict__ W, const float* __restrict__ tbl,
               float* __restrict__ wb) {
    int p = blockIdx.x;          // 0..95
    int lane = threadIdx.x;      // 0..63
    const float* wr = W + (size_t)p * SEQL + lane * 8;
    float4 wa = *(const float4*)(wr);
    float4 wz = *(const float4*)(wr + 4);
    float wv[8] = {wa.x, wa.y, wa.z, wa.w, wz.x, wz.y, wz.z, wz.w};
    #pragma unroll
    for (int j = 0; j < NB; ++j) {
        const float* bj = tbl + j * SEQL + lane * 8;
        float4 b0 = *(const float4*)bj;
        float4 b1 = *(const float4*)(bj + 4);
        float bb[8] = {b0.x, b0.y, b0.z, b0.w, b1.x, b1.y, b1.z, b1.w};
        float acc = 0.f;
        #pragma unroll
        for (int e = 0; e < 8; ++e) acc += wv[e] * bb[e];
        float s = wave_sum_bcast(acc);
        if (lane == 0) wb[p * WBPAD + j] = s;
    }
}

// ---------------- main kernel: symmetry-folded, register double-buffered ---------
// Lane l owns elements s0 = 4l (0..255) and s1 = 4l+256 of each row.
// b_k(s+256) = (-1)^k b_k(s): even-k coefs use u = x[s0]+x[s1], odd-k use v = x[s0]-x[s1].
__global__ __launch_bounds__(256)
void detrend_kernel(const float* __restrict__ x, const float* __restrict__ bias,
                    const float* __restrict__ tbl, const float* __restrict__ wb,
                    float* __restrict__ fc, float* __restrict__ resid, int nrows) {
    const int lane = threadIdx.x & 63;
    const int wid  = threadIdx.x >> 6;
    const int gw   = blockIdx.x * (blockDim.x >> 6) + wid;
    const int nw   = gridDim.x * (blockDim.x >> 6);
    const int step = nw * RU;

    // basis values at s = 4*lane + e, e=0..3 (36 VGPRs). j=0 is all-ones (skipped).
    float bas[NB][4];
    #pragma unroll
    for (int j = 1; j < NB; ++j) {
        float4 b0 = *(const float4*)(tbl + j * SEQL + lane * 4);
        bas[j][0] = b0.x; bas[j][1] = b0.y; bas[j][2] = b0.z; bas[j][3] = b0.w;
    }
    const int p0 = lane;
    const int p1 = 64 + lane;
    float wb0[NB], wb1[NB], bv0, bv1 = 0.f;
    #pragma unroll
    for (int j = 0; j < NB; ++j) wb0[j] = wb[p0 * WBPAD + j];
    bv0 = bias[p0];
    if (lane < 32) {
        #pragma unroll
        for (int j = 0; j < NB; ++j) wb1[j] = wb[p1 * WBPAD + j];
        bv1 = bias[p1];
    }

    float4 bufA0[RU], bufA1[RU];   // x[s0..s0+3] for each row, two buffers
    float4 bufB0[RU], bufB1[RU];   // x[s1..s1+3]

    int r = gw * RU;
    if (r >= nrows) return;

    // ---- prologue: load first tile into buf0 ----
    #pragma unroll
    for (int u = 0; u < RU; ++u) {
        const float* xr = x + (size_t)(r + u) * SEQL + lane * 4;
        bufA0[u] = *(const float4*)xr;
        bufB0[u] = *(const float4*)(xr + 256);
    }

    #define PROCESS(BA, BB, RR)                                                     \
    {                                                                               \
        _Pragma("unroll")                                                           \
        for (int u = 0; u < RU; ++u) {                                              \
            float ue[4], ve[4];                                                     \
            ue[0]=BA[u].x+BB[u].x; ue[1]=BA[u].y+BB[u].y;                           \
            ue[2]=BA[u].z+BB[u].z; ue[3]=BA[u].w+BB[u].w;                           \
            ve[0]=BA[u].x-BB[u].x; ve[1]=BA[u].y-BB[u].y;                           \
            ve[2]=BA[u].z-BB[u].z; ve[3]=BA[u].w-BB[u].w;                           \
            float acc[NB];                                                          \
            acc[0] = (ue[0]+ue[1]) + (ue[2]+ue[3]);                                 \
            acc[1]=0.f; acc[2]=0.f; acc[5]=0.f; acc[6]=0.f;  /* odd k: use v */     \
            acc[3]=0.f; acc[4]=0.f; acc[7]=0.f; acc[8]=0.f;  /* even k: use u */    \
            _Pragma("unroll")                                                       \
            for (int e = 0; e < 4; ++e) {                                           \
                acc[1] += ve[e]*bas[1][e]; acc[2] += ve[e]*bas[2][e];               \
                acc[5] += ve[e]*bas[5][e]; acc[6] += ve[e]*bas[6][e];               \
                acc[3] += ue[e]*bas[3][e]; acc[4] += ue[e]*bas[4][e];               \
                acc[7] += ue[e]*bas[7][e]; acc[8] += ue[e]*bas[8][e];               \
            }                                                                       \
            acc[0] *= (1.0f / SEQL);                                                \
            _Pragma("unroll")                                                       \
            for (int j = 1; j < NB; ++j) acc[j] *= (2.0f / SEQL);                   \
            float c[NB];                                                            \
            _Pragma("unroll")                                                       \
            for (int j = 0; j < NB; ++j) c[j] = wave_sum_bcast(acc[j]);             \
            float r0v[4], r1v[4];                                                   \
            _Pragma("unroll")                                                       \
            for (int e = 0; e < 4; ++e) {                                           \
                float te = c[0] + c[3]*bas[3][e] + c[4]*bas[4][e]                   \
                                + c[7]*bas[7][e] + c[8]*bas[8][e];                  \
                float to = c[1]*bas[1][e] + c[2]*bas[2][e]                          \
                         + c[5]*bas[5][e] + c[6]*bas[6][e];                         \
                float av = (e==0)?BA[u].x:(e==1)?BA[u].y:(e==2)?BA[u].z:BA[u].w;    \
                float bv = (e==0)?BB[u].x:(e==1)?BB[u].y:(e==2)?BB[u].z:BB[u].w;    \
                r0v[e] = av - (te + to);                                            \
                r1v[e] = bv - (te - to);                                            \
            }                                                                       \
            float* rr = resid + (size_t)((RR) + u) * SEQL + lane * 4;               \
            fvec4 s0v = {r0v[0], r0v[1], r0v[2], r0v[3]};                           \
            fvec4 s1v = {r1v[0], r1v[1], r1v[2], r1v[3]};                           \
            __builtin_nontemporal_store(s0v, (fvec4*)rr);                           \
            __builtin_nontemporal_store(s1v, (fvec4*)(rr + 256));                   \
            float* fr = fc + (size_t)((RR) + u) * PREDL;                            \
            float f0 = bv0;                                                         \
            _Pragma("unroll")                                                       \
            for (int j = 0; j < NB; ++j) f0 += c[j] * wb0[j];                       \
            __builtin_nontemporal_store(f0, fr + p0);                               \
            if (lane < 32) {                                                        \
                float f1 = bv1;                                                     \
                _Pragma("unroll")                                                   \
                for (int j = 0; j < NB; ++j) f1 += c[j] * wb1[j];                   \
                __builtin_nontemporal_store(f1, fr + p1);                           \
            }                                                                       \
        }                                                                           \
    }

    // ---- main loop, unrolled x2 with named buffers (no runtime buffer index) ----
    while (true) {
        int r1 = r + step;
        if (r1 < nrows) {
            #pragma unroll
            for (int u = 0; u < RU; ++u) {
                const float* xr = x + (size_t)(r1 + u) * SEQL + lane * 4;
                bufA1[u] = *(const float4*)xr;
                bufB1[u] = *(const float4*)(xr + 256);
            }
        }
        PROCESS(bufA0, bufB0, r);
        if (r1 >= nrows) break;

        int r2 = r1 + step;
        if (r2 < nrows) {
            #pragma unroll
            for (int u = 0; u < RU; ++u) {
                const float* xr = x + (size_t)(r2 + u) * SEQL + lane * 4;
                bufA0[u] = *(const float4*)xr;
                bufB0[u] = *(const float4*)(xr + 256);
            }
        }
        PROCESS(bufA1, bufB1, r1);
        if (r2 >= nrows) break;
        r = r2;
    }
    #undef PROCESS
}

extern "C" void kernel_launch(void* const* d_in, const int* in_sizes, int n_in,
                              void* d_out, int out_size, void* d_ws, size_t ws_size,
                              hipStream_t stream) {
    const float* x = (const float*)d_in[0];
    const float* W = (const float*)d_in[1];
    const float* b = (const float*)d_in[2];
    float* fc = (float*)d_out;
    const int nrows = in_sizes[0] / SEQL;            // 65536
    float* resid = fc + (size_t)nrows * PREDL;
    float* tbl = (float*)d_ws;                       // 9*512 floats
    float* wb  = tbl + NB * SEQL;                    // 96*12 floats

    hipLaunchKernelGGL(basis_kernel, dim3(1), dim3(SEQL), 0, stream, tbl);
    hipLaunchKernelGGL(wb_kernel, dim3(PREDL), dim3(64), 0, stream, W, tbl, wb);
    // 1024 blocks x 4 waves x RU=4 rows = 16384 rows/step -> 4 staggered iterations
    hipLaunchKernelGGL(detrend_kernel, dim3(1024), dim3(256), 0, stream,
                       x, b, tbl, wb, fc, resid, nrows);
}

// Round 9
// 55.514 us; speedup vs baseline: 1.7935x; 1.0893x over previous
//
#include <hip/hip_runtime.h>

#define SEQL 512
#define PREDL 96
#define NB 9          // 1 + 2*4 basis functions (DC, cos/sin k=1..4)
#define WBPAD 12      // padded stride for WB rows
#define RU 4          // rows per wave per iteration

typedef float fvec4 __attribute__((ext_vector_type(4)));

#define TWO_PI_OVER_SEQL 0.012271846303085130f   // 2*pi/512, fp32-rounded

// Full-wave sum via DPP (VALU pipe only), broadcast through SGPR readlane(63).
__device__ __forceinline__ float wave_sum_bcast(float v) {
    int t;
    t = __builtin_amdgcn_update_dpp(0, __float_as_int(v), 0x111, 0xf, 0xf, true); v += __int_as_float(t); // shr 1
    t = __builtin_amdgcn_update_dpp(0, __float_as_int(v), 0x112, 0xf, 0xf, true); v += __int_as_float(t); // shr 2
    t = __builtin_amdgcn_update_dpp(0, __float_as_int(v), 0x114, 0xf, 0xf, true); v += __int_as_float(t); // shr 4
    t = __builtin_amdgcn_update_dpp(0, __float_as_int(v), 0x118, 0xf, 0xf, true); v += __int_as_float(t); // shr 8
    t = __builtin_amdgcn_update_dpp(0, __float_as_int(v), 0x142, 0xf, 0xf, true); v += __int_as_float(t); // bcast15
    t = __builtin_amdgcn_update_dpp(0, __float_as_int(v), 0x143, 0xf, 0xf, true); v += __int_as_float(t); // bcast31
    return __int_as_float(__builtin_amdgcn_readlane(__float_as_int(v), 63));
}

// basis value pair for harmonic k at position s (exact mod-512 reduction)
__device__ __forceinline__ void basis_cs(int k, int s, float* cs, float* sn) {
    int m = (k * s) & (SEQL - 1);
    float ang = (float)m * TWO_PI_OVER_SEQL;
    __sincosf(ang, sn, cs);
}

// ---------------- setup: WB[p][j] = basis_j . W[p]  (basis inline) ---------------
__global__ __launch_bounds__(64)
void wb_kernel(const float* __restrict__ W, float* __restrict__ wb) {
    int p = blockIdx.x;          // 0..95
    int lane = threadIdx.x;      // 0..63
    const float* wr = W + (size_t)p * SEQL + lane * 8;
    float4 wa = *(const float4*)(wr);
    float4 wz = *(const float4*)(wr + 4);
    float wv[8] = {wa.x, wa.y, wa.z, wa.w, wz.x, wz.y, wz.z, wz.w};
    float acc[NB];
    acc[0] = ((wv[0]+wv[1])+(wv[2]+wv[3])) + ((wv[4]+wv[5])+(wv[6]+wv[7]));
    #pragma unroll
    for (int j = 1; j < NB; ++j) acc[j] = 0.f;
    #pragma unroll
    for (int e = 0; e < 8; ++e) {
        int s = lane * 8 + e;
        #pragma unroll
        for (int k = 1; k <= 4; ++k) {
            float cs, sn;
            basis_cs(k, s, &cs, &sn);
            acc[2*k-1] += wv[e] * cs;
            acc[2*k  ] += wv[e] * sn;
        }
    }
    #pragma unroll
    for (int j = 0; j < NB; ++j) {
        float sum = wave_sum_bcast(acc[j]);
        if (lane == 0) wb[p * WBPAD + j] = sum;
    }
}

// ---------------- main kernel: symmetry-folded, register double-buffered ---------
// Lane l owns elements s0 = 4l (0..255) and s1 = 4l+256 of each row.
// b_k(s+256) = (-1)^k b_k(s): even-k coefs use u = x[s0]+x[s1], odd-k use v = x[s0]-x[s1].
__global__ __launch_bounds__(256)
void detrend_kernel(const float* __restrict__ x, const float* __restrict__ bias,
                    const float* __restrict__ wb,
                    float* __restrict__ fc, float* __restrict__ resid, int nrows) {
    const int lane = threadIdx.x & 63;
    const int wid  = threadIdx.x >> 6;
    const int gw   = blockIdx.x * (blockDim.x >> 6) + wid;
    const int nw   = gridDim.x * (blockDim.x >> 6);
    const int step = nw * RU;

    // basis values at s = 4*lane + e, e=0..3, computed inline (no table reads).
    // bas[0] (DC) unused.
    float bas[NB][4];
    #pragma unroll
    for (int e = 0; e < 4; ++e) {
        int s = 4 * lane + e;
        #pragma unroll
        for (int k = 1; k <= 4; ++k) {
            float cs, sn;
            basis_cs(k, s, &cs, &sn);
            bas[2*k-1][e] = cs;
            bas[2*k  ][e] = sn;
        }
    }
    const int p0 = lane;
    const int p1 = 64 + lane;
    float wb0[NB], wb1[NB], bv0, bv1 = 0.f;
    #pragma unroll
    for (int j = 0; j < NB; ++j) wb0[j] = wb[p0 * WBPAD + j];
    bv0 = bias[p0];
    if (lane < 32) {
        #pragma unroll
        for (int j = 0; j < NB; ++j) wb1[j] = wb[p1 * WBPAD + j];
        bv1 = bias[p1];
    }

    float4 bufA0[RU], bufA1[RU];   // x[s0..s0+3] for each row, two buffers
    float4 bufB0[RU], bufB1[RU];   // x[s1..s1+3]

    int r = gw * RU;
    if (r >= nrows) return;

    // ---- prologue: load first tile into buf0 ----
    #pragma unroll
    for (int u = 0; u < RU; ++u) {
        const float* xr = x + (size_t)(r + u) * SEQL + lane * 4;
        bufA0[u] = *(const float4*)xr;
        bufB0[u] = *(const float4*)(xr + 256);
    }

    #define PROCESS(BA, BB, RR)                                                     \
    {                                                                               \
        _Pragma("unroll")                                                           \
        for (int u = 0; u < RU; ++u) {                                              \
            float ue[4], ve[4];                                                     \
            ue[0]=BA[u].x+BB[u].x; ue[1]=BA[u].y+BB[u].y;                           \
            ue[2]=BA[u].z+BB[u].z; ue[3]=BA[u].w+BB[u].w;                           \
            ve[0]=BA[u].x-BB[u].x; ve[1]=BA[u].y-BB[u].y;                           \
            ve[2]=BA[u].z-BB[u].z; ve[3]=BA[u].w-BB[u].w;                           \
            float acc[NB];                                                          \
            acc[0] = (ue[0]+ue[1]) + (ue[2]+ue[3]);                                 \
            acc[1]=0.f; acc[2]=0.f; acc[5]=0.f; acc[6]=0.f;  /* odd k: use v */     \
            acc[3]=0.f; acc[4]=0.f; acc[7]=0.f; acc[8]=0.f;  /* even k: use u */    \
            _Pragma("unroll")                                                       \
            for (int e = 0; e < 4; ++e) {                                           \
                acc[1] += ve[e]*bas[1][e]; acc[2] += ve[e]*bas[2][e];               \
                acc[5] += ve[e]*bas[5][e]; acc[6] += ve[e]*bas[6][e];               \
                acc[3] += ue[e]*bas[3][e]; acc[4] += ue[e]*bas[4][e];               \
                acc[7] += ue[e]*bas[7][e]; acc[8] += ue[e]*bas[8][e];               \
            }                                                                       \
            acc[0] *= (1.0f / SEQL);                                                \
            _Pragma("unroll")                                                       \
            for (int j = 1; j < NB; ++j) acc[j] *= (2.0f / SEQL);                   \
            float c[NB];                                                            \
            _Pragma("unroll")                                                       \
            for (int j = 0; j < NB; ++j) c[j] = wave_sum_bcast(acc[j]);             \
            float r0v[4], r1v[4];                                                   \
            _Pragma("unroll")                                                       \
            for (int e = 0; e < 4; ++e) {                                           \
                float te = c[0] + c[3]*bas[3][e] + c[4]*bas[4][e]                   \
                                + c[7]*bas[7][e] + c[8]*bas[8][e];                  \
                float to = c[1]*bas[1][e] + c[2]*bas[2][e]                          \
                         + c[5]*bas[5][e] + c[6]*bas[6][e];                         \
                float av = (e==0)?BA[u].x:(e==1)?BA[u].y:(e==2)?BA[u].z:BA[u].w;    \
                float bv = (e==0)?BB[u].x:(e==1)?BB[u].y:(e==2)?BB[u].z:BB[u].w;    \
                r0v[e] = av - (te + to);                                            \
                r1v[e] = bv - (te - to);                                            \
            }                                                                       \
            float* rr = resid + (size_t)((RR) + u) * SEQL + lane * 4;               \
            fvec4 s0v = {r0v[0], r0v[1], r0v[2], r0v[3]};                           \
            fvec4 s1v = {r1v[0], r1v[1], r1v[2], r1v[3]};                           \
            __builtin_nontemporal_store(s0v, (fvec4*)rr);                           \
            __builtin_nontemporal_store(s1v, (fvec4*)(rr + 256));                   \
            float* fr = fc + (size_t)((RR) + u) * PREDL;                            \
            float f0 = bv0;                                                         \
            _Pragma("unroll")                                                       \
            for (int j = 0; j < NB; ++j) f0 += c[j] * wb0[j];                       \
            __builtin_nontemporal_store(f0, fr + p0);                               \
            if (lane < 32) {                                                        \
                float f1 = bv1;                                                     \
                _Pragma("unroll")                                                   \
                for (int j = 0; j < NB; ++j) f1 += c[j] * wb1[j];                   \
                __builtin_nontemporal_store(f1, fr + p1);                           \
            }                                                                       \
        }                                                                           \
    }

    // ---- main loop, unrolled x2 with named buffers (no runtime buffer index) ----
    while (true) {
        int r1 = r + step;
        if (r1 < nrows) {
            #pragma unroll
            for (int u = 0; u < RU; ++u) {
                const float* xr = x + (size_t)(r1 + u) * SEQL + lane * 4;
                bufA1[u] = *(const float4*)xr;
                bufB1[u] = *(const float4*)(xr + 256);
            }
        }
        PROCESS(bufA0, bufB0, r);
        if (r1 >= nrows) break;

        int r2 = r1 + step;
        if (r2 < nrows) {
            #pragma unroll
            for (int u = 0; u < RU; ++u) {
                const float* xr = x + (size_t)(r2 + u) * SEQL + lane * 4;
                bufA0[u] = *(const float4*)xr;
                bufB0[u] = *(const float4*)(xr + 256);
            }
        }
        PROCESS(bufA1, bufB1, r1);
        if (r2 >= nrows) break;
        r = r2;
    }
    #undef PROCESS
}

extern "C" void kernel_launch(void* const* d_in, const int* in_sizes, int n_in,
                              void* d_out, int out_size, void* d_ws, size_t ws_size,
                              hipStream_t stream) {
    const float* x = (const float*)d_in[0];
    const float* W = (const float*)d_in[1];
    const float* b = (const float*)d_in[2];
    float* fc = (float*)d_out;
    const int nrows = in_sizes[0] / SEQL;            // 65536
    float* resid = fc + (size_t)nrows * PREDL;
    float* wb  = (float*)d_ws;                       // 96*12 floats

    hipLaunchKernelGGL(wb_kernel, dim3(PREDL), dim3(64), 0, stream, W, wb);
    // 1024 blocks x 4 waves x RU=4 rows = 16384 rows/step -> 4 staggered iterations
    hipLaunchKernelGGL(detrend_kernel, dim3(1024), dim3(256), 0, stream,
                       x, b, wb, fc, resid, nrows);
}

// Round 10
// 54.617 us; speedup vs baseline: 1.8229x; 1.0164x over previous
//
#include <hip/hip_runtime.h>

#define SEQL 512
#define PREDL 96
#define NB 9          // 1 + 2*4 basis functions (DC, cos/sin k=1..4)
#define WBPAD 12      // padded stride for WB rows
#define RU 2          // rows per wave per iteration (small -> VGPR < 128 cliff)

typedef float fvec4 __attribute__((ext_vector_type(4)));

#define TWO_PI_OVER_SEQL 0.012271846303085130f   // 2*pi/512, fp32-rounded

// Full-wave sum via DPP (VALU pipe only), broadcast through SGPR readlane(63).
__device__ __forceinline__ float wave_sum_bcast(float v) {
    int t;
    t = __builtin_amdgcn_update_dpp(0, __float_as_int(v), 0x111, 0xf, 0xf, true); v += __int_as_float(t); // shr 1
    t = __builtin_amdgcn_update_dpp(0, __float_as_int(v), 0x112, 0xf, 0xf, true); v += __int_as_float(t); // shr 2
    t = __builtin_amdgcn_update_dpp(0, __float_as_int(v), 0x114, 0xf, 0xf, true); v += __int_as_float(t); // shr 4
    t = __builtin_amdgcn_update_dpp(0, __float_as_int(v), 0x118, 0xf, 0xf, true); v += __int_as_float(t); // shr 8
    t = __builtin_amdgcn_update_dpp(0, __float_as_int(v), 0x142, 0xf, 0xf, true); v += __int_as_float(t); // bcast15
    t = __builtin_amdgcn_update_dpp(0, __float_as_int(v), 0x143, 0xf, 0xf, true); v += __int_as_float(t); // bcast31
    return __int_as_float(__builtin_amdgcn_readlane(__float_as_int(v), 63));
}

// basis value pair for harmonic k at position s (exact mod-512 reduction)
__device__ __forceinline__ void basis_cs(int k, int s, float* cs, float* sn) {
    int m = (k * s) & (SEQL - 1);
    float ang = (float)m * TWO_PI_OVER_SEQL;
    __sincosf(ang, sn, cs);
}

// ---------------- setup: WB[p][j] = basis_j . W[p]  (basis inline) ---------------
__global__ __launch_bounds__(64)
void wb_kernel(const float* __restrict__ W, float* __restrict__ wb) {
    int p = blockIdx.x;          // 0..95
    int lane = threadIdx.x;      // 0..63
    const float* wr = W + (size_t)p * SEQL + lane * 8;
    float4 wa = *(const float4*)(wr);
    float4 wz = *(const float4*)(wr + 4);
    float wv[8] = {wa.x, wa.y, wa.z, wa.w, wz.x, wz.y, wz.z, wz.w};
    float acc[NB];
    acc[0] = ((wv[0]+wv[1])+(wv[2]+wv[3])) + ((wv[4]+wv[5])+(wv[6]+wv[7]));
    #pragma unroll
    for (int j = 1; j < NB; ++j) acc[j] = 0.f;
    #pragma unroll
    for (int e = 0; e < 8; ++e) {
        int s = lane * 8 + e;
        #pragma unroll
        for (int k = 1; k <= 4; ++k) {
            float cs, sn;
            basis_cs(k, s, &cs, &sn);
            acc[2*k-1] += wv[e] * cs;
            acc[2*k  ] += wv[e] * sn;
        }
    }
    #pragma unroll
    for (int j = 0; j < NB; ++j) {
        float sum = wave_sum_bcast(acc[j]);
        if (lane == 0) wb[p * WBPAD + j] = sum;
    }
}

// ---------------- main kernel: symmetry-folded, register double-buffered ---------
// Lane l owns elements s0 = 4l (0..255) and s1 = 4l+256 of each row.
// b_k(s+256) = (-1)^k b_k(s): even-k coefs use u = x[s0]+x[s1], odd-k use v = x[s0]-x[s1].
__global__ __launch_bounds__(256, 4)   // min 4 waves/EU -> VGPR capped at 128
void detrend_kernel(const float* __restrict__ x, const float* __restrict__ bias,
                    const float* __restrict__ wb,
                    float* __restrict__ fc, float* __restrict__ resid, int nrows) {
    const int lane = threadIdx.x & 63;
    const int wid  = threadIdx.x >> 6;
    const int gw   = blockIdx.x * (blockDim.x >> 6) + wid;
    const int nw   = gridDim.x * (blockDim.x >> 6);
    const int step = nw * RU;

    // basis values at s = 4*lane + e, e=0..3, computed inline (no table reads).
    // bas[0] (DC) unused.
    float bas[NB][4];
    #pragma unroll
    for (int e = 0; e < 4; ++e) {
        int s = 4 * lane + e;
        #pragma unroll
        for (int k = 1; k <= 4; ++k) {
            float cs, sn;
            basis_cs(k, s, &cs, &sn);
            bas[2*k-1][e] = cs;
            bas[2*k  ][e] = sn;
        }
    }
    const int p0 = lane;
    const int p1 = 64 + lane;
    float wb0[NB], wb1[NB], bv0, bv1 = 0.f;
    #pragma unroll
    for (int j = 0; j < NB; ++j) wb0[j] = wb[p0 * WBPAD + j];
    bv0 = bias[p0];
    if (lane < 32) {
        #pragma unroll
        for (int j = 0; j < NB; ++j) wb1[j] = wb[p1 * WBPAD + j];
        bv1 = bias[p1];
    }

    float4 bufA0[RU], bufA1[RU];   // x[s0..s0+3] for each row, two buffers
    float4 bufB0[RU], bufB1[RU];   // x[s1..s1+3]

    int r = gw * RU;
    if (r >= nrows) return;

    // ---- prologue: load first tile into buf0 ----
    #pragma unroll
    for (int u = 0; u < RU; ++u) {
        const float* xr = x + (size_t)(r + u) * SEQL + lane * 4;
        bufA0[u] = *(const float4*)xr;
        bufB0[u] = *(const float4*)(xr + 256);
    }

    #define PROCESS(BA, BB, RR)                                                     \
    {                                                                               \
        _Pragma("unroll")                                                           \
        for (int u = 0; u < RU; ++u) {                                              \
            float ue[4], ve[4];                                                     \
            ue[0]=BA[u].x+BB[u].x; ue[1]=BA[u].y+BB[u].y;                           \
            ue[2]=BA[u].z+BB[u].z; ue[3]=BA[u].w+BB[u].w;                           \
            ve[0]=BA[u].x-BB[u].x; ve[1]=BA[u].y-BB[u].y;                           \
            ve[2]=BA[u].z-BB[u].z; ve[3]=BA[u].w-BB[u].w;                           \
            float acc[NB];                                                          \
            acc[0] = (ue[0]+ue[1]) + (ue[2]+ue[3]);                                 \
            acc[1]=0.f; acc[2]=0.f; acc[5]=0.f; acc[6]=0.f;  /* odd k: use v */     \
            acc[3]=0.f; acc[4]=0.f; acc[7]=0.f; acc[8]=0.f;  /* even k: use u */    \
            _Pragma("unroll")                                                       \
            for (int e = 0; e < 4; ++e) {                                           \
                acc[1] += ve[e]*bas[1][e]; acc[2] += ve[e]*bas[2][e];               \
                acc[5] += ve[e]*bas[5][e]; acc[6] += ve[e]*bas[6][e];               \
                acc[3] += ue[e]*bas[3][e]; acc[4] += ue[e]*bas[4][e];               \
                acc[7] += ue[e]*bas[7][e]; acc[8] += ue[e]*bas[8][e];               \
            }                                                                       \
            acc[0] *= (1.0f / SEQL);                                                \
            _Pragma("unroll")                                                       \
            for (int j = 1; j < NB; ++j) acc[j] *= (2.0f / SEQL);                   \
            float c[NB];                                                            \
            _Pragma("unroll")                                                       \
            for (int j = 0; j < NB; ++j) c[j] = wave_sum_bcast(acc[j]);             \
            float r0v[4], r1v[4];                                                   \
            _Pragma("unroll")                                                       \
            for (int e = 0; e < 4; ++e) {                                           \
                float te = c[0] + c[3]*bas[3][e] + c[4]*bas[4][e]                   \
                                + c[7]*bas[7][e] + c[8]*bas[8][e];                  \
                float to = c[1]*bas[1][e] + c[2]*bas[2][e]                          \
                         + c[5]*bas[5][e] + c[6]*bas[6][e];                         \
                float av = (e==0)?BA[u].x:(e==1)?BA[u].y:(e==2)?BA[u].z:BA[u].w;    \
                float bv = (e==0)?BB[u].x:(e==1)?BB[u].y:(e==2)?BB[u].z:BB[u].w;    \
                r0v[e] = av - (te + to);                                            \
                r1v[e] = bv - (te - to);                                            \
            }                                                                       \
            float* rr = resid + (size_t)((RR) + u) * SEQL + lane * 4;               \
            fvec4 s0v = {r0v[0], r0v[1], r0v[2], r0v[3]};                           \
            fvec4 s1v = {r1v[0], r1v[1], r1v[2], r1v[3]};                           \
            __builtin_nontemporal_store(s0v, (fvec4*)rr);                           \
            __builtin_nontemporal_store(s1v, (fvec4*)(rr + 256));                   \
            float* fr = fc + (size_t)((RR) + u) * PREDL;                            \
            float f0 = bv0;                                                         \
            _Pragma("unroll")                                                       \
            for (int j = 0; j < NB; ++j) f0 += c[j] * wb0[j];                       \
            __builtin_nontemporal_store(f0, fr + p0);                               \
            if (lane < 32) {                                                        \
                float f1 = bv1;                                                     \
                _Pragma("unroll")                                                   \
                for (int j = 0; j < NB; ++j) f1 += c[j] * wb1[j];                   \
                __builtin_nontemporal_store(f1, fr + p1);                           \
            }                                                                       \
        }                                                                           \
    }

    // ---- main loop, unrolled x2 with named buffers (no runtime buffer index) ----
    while (true) {
        int r1 = r + step;
        if (r1 < nrows) {
            #pragma unroll
            for (int u = 0; u < RU; ++u) {
                const float* xr = x + (size_t)(r1 + u) * SEQL + lane * 4;
                bufA1[u] = *(const float4*)xr;
                bufB1[u] = *(const float4*)(xr + 256);
            }
        }
        PROCESS(bufA0, bufB0, r);
        if (r1 >= nrows) break;

        int r2 = r1 + step;
        if (r2 < nrows) {
            #pragma unroll
            for (int u = 0; u < RU; ++u) {
                const float* xr = x + (size_t)(r2 + u) * SEQL + lane * 4;
                bufA0[u] = *(const float4*)xr;
                bufB0[u] = *(const float4*)(xr + 256);
            }
        }
        PROCESS(bufA1, bufB1, r1);
        if (r2 >= nrows) break;
        r = r2;
    }
    #undef PROCESS
}

extern "C" void kernel_launch(void* const* d_in, const int* in_sizes, int n_in,
                              void* d_out, int out_size, void* d_ws, size_t ws_size,
                              hipStream_t stream) {
    const float* x = (const float*)d_in[0];
    const float* W = (const float*)d_in[1];
    const float* b = (const float*)d_in[2];
    float* fc = (float*)d_out;
    const int nrows = in_sizes[0] / SEQL;            // 65536
    float* resid = fc + (size_t)nrows * PREDL;
    float* wb  = (float*)d_ws;                       // 96*12 floats

    hipLaunchKernelGGL(wb_kernel, dim3(PREDL), dim3(64), 0, stream, W, wb);
    // 2048 blocks x 4 waves x RU=2 rows = 16384 rows/step -> 4 staggered iterations
    hipLaunchKernelGGL(detrend_kernel, dim3(2048), dim3(256), 0, stream,
                       x, b, wb, fc, resid, nrows);
}